// Round 7
// baseline (313.208 us; speedup 1.0000x reference)
//
#include <hip/hip_runtime.h>
#include <hip/hip_cooperative_groups.h>
#include <math.h>

namespace cg = cooperative_groups;

#define D_IN 131072
#define H 512
#define G4 2048      // 4*H
#define OUTN 16384   // 128*128

// ---- output flat offsets ----
// g: [0,16384)  step:16384  m_c:16385  h0:@16386  h1:@16898  c0:@17410  c1:@17922
#define OFF_STEP 16384
#define OFF_MC   16385
#define OFF_H0   16386
#define OFF_H1   16898
#define OFF_C0   17410
#define OFF_C1   17922

__device__ __forceinline__ float sigmoidf_(float x) {
    return 1.0f / (1.0f + __expf(-x));
}

__device__ __forceinline__ float dot4(float4 a, float4 b) {
    return a.x*b.x + a.y*b.y + a.z*b.z + a.w*b.w;
}

// non-temporal float4 load (single-use weight streams: don't pollute L2)
typedef float f4v __attribute__((ext_vector_type(4)));
__device__ __forceinline__ float4 ntload4(const float4* p) {
    f4v v = __builtin_nontemporal_load((const f4v*)p);
    float4 r; r.x = v.x; r.y = v.y; r.z = v.z; r.w = v.w;
    return r;
}

// ---------------------------------------------------------------------------
// Fully-fused cooperative kernel. 512 blocks x 256 threads (2 blocks/CU,
// co-resident). grid.sync() replaces inter-kernel launch gaps.
//  Phase 1: gates1 = W_ih1.grad + W_hh1.h_in0 + biases (R6's k_gemv1p verbatim:
//           4 contiguous rows/block, NT W loads, 512 HBM streams of 2 MB).
//  Phase 2: recompute h0 from gates1 in LDS; 4 gates2 rows/block (1/wave);
//           block 0 writes h0/c0 + m_c.
//  Phase 3: recompute h1 from gates2 in LDS; 32 W1 rows/block (8/wave);
//           block 0 writes h1/c1 + step_size.
// ---------------------------------------------------------------------------
__global__ __launch_bounds__(256) void k_fused(
    const float* __restrict__ U, const float* __restrict__ V,
    const float* __restrict__ hidden, const float* __restrict__ cell,
    const float* __restrict__ Wih1, const float* __restrict__ Whh1,
    const float* __restrict__ bih1, const float* __restrict__ bhh1,
    const float* __restrict__ Wih2, const float* __restrict__ Whh2,
    const float* __restrict__ bih2, const float* __restrict__ bhh2,
    const float* __restrict__ W1,   const float* __restrict__ b1,
    const float* __restrict__ W2,   const float* __restrict__ b2,
    const float* __restrict__ W3,   const float* __restrict__ b3,
    float* __restrict__ gates1, float* __restrict__ gates2,
    float* __restrict__ out)
{
    cg::grid_group grid = cg::this_grid();
    __shared__ float hs[H];
    __shared__ float red[4];
    const int t = threadIdx.x;
    const int wv = t >> 6, lane = t & 63;

    // ---------------- Phase 1: big GEMV ----------------
    {
        const float4* __restrict__ U4 = (const float4*)U;
        const float4* __restrict__ V4 = (const float4*)V;
        const float4* __restrict__ h4 = (const float4*)hidden;  // hidden[0]
        #pragma unroll 1
        for (int i = 0; i < 4; ++i) {
            const int r = blockIdx.x * 4 + i;
            const float4* __restrict__ Wrow = (const float4*)(Wih1 + (size_t)r * D_IN);
            float acc = 0.0f;
            #pragma unroll 4
            for (int idx = t; idx < 16384; idx += 256) {
                acc += dot4(ntload4(&Wrow[idx]), U4[idx]);
            }
            #pragma unroll 4
            for (int idx = t; idx < 16384; idx += 256) {
                acc += dot4(ntload4(&Wrow[idx + 16384]), V4[idx]);
            }
            if (t < 128) {
                const float4* __restrict__ Wh4 = (const float4*)(Whh1 + (size_t)r * H);
                acc += dot4(ntload4(&Wh4[t]), h4[t]);
            }
            #pragma unroll
            for (int off = 32; off > 0; off >>= 1) acc += __shfl_down(acc, off);
            if ((t & 63) == 0) red[t >> 6] = acc;
            __syncthreads();
            if (t == 0) {
                gates1[r] = red[0] + red[1] + red[2] + red[3] + bih1[r] + bhh1[r];
            }
            __syncthreads();   // red reused next row
        }
    }
    grid.sync();

    // ---------------- Phase 2: cell1 + gemv2 ----------------
    {
        // recompute h0 into LDS (each thread: entries t and t+256)
        #pragma unroll
        for (int k = 0; k < 2; ++k) {
            const int j = t + k * 256;
            float ig = sigmoidf_(gates1[j]);
            float fg = sigmoidf_(gates1[H + j]);
            float gg = tanhf(gates1[2*H + j]);
            float og = sigmoidf_(gates1[3*H + j]);
            float c  = fg * cell[j] + ig * gg;   // cell[0]
            float h  = og * tanhf(c);
            hs[j] = h;
            if (blockIdx.x == 0) {
                out[OFF_H0 + j] = h;
                out[OFF_C0 + j] = c;
            }
        }
        __syncthreads();
        const int row = blockIdx.x * 4 + wv;
        const float4* __restrict__ Wr = (const float4*)(Wih2 + (size_t)row * H);
        const float4* __restrict__ Hr = (const float4*)(Whh2 + (size_t)row * H);
        const float4* h4 = (const float4*)hs;
        const float4* __restrict__ y4 = (const float4*)(hidden + H);  // hidden[1]
        float acc = dot4(ntload4(&Wr[lane]),      h4[lane])
                  + dot4(ntload4(&Hr[lane]),      y4[lane])
                  + dot4(ntload4(&Wr[lane + 64]), h4[lane + 64])
                  + dot4(ntload4(&Hr[lane + 64]), y4[lane + 64]);
        #pragma unroll
        for (int off = 32; off > 0; off >>= 1) acc += __shfl_down(acc, off);
        if (lane == 0) gates2[row] = acc + bih2[row] + bhh2[row];

        if (blockIdx.x == 0) {
            // m_c = clip(2*clip(h0.W3 + b3, 0, 1), 0, 1)
            float p = hs[t] * W3[t] + hs[t + 256] * W3[t + 256];
            #pragma unroll
            for (int off = 32; off > 0; off >>= 1) p += __shfl_down(p, off);
            __syncthreads();          // red free (phase-1 use done grid-wide)
            if (lane == 0) red[wv] = p;
            __syncthreads();
            if (t == 0) {
                float v = red[0] + red[1] + red[2] + red[3] + b3[0];
                v = fminf(fmaxf(v, 0.0f), 1.0f);
                out[OFF_MC] = fminf(2.0f * v, 1.0f);
            }
        }
    }
    grid.sync();

    // ---------------- Phase 3: cell2 + out_g ----------------
    {
        __syncthreads();   // hs reuse
        #pragma unroll
        for (int k = 0; k < 2; ++k) {
            const int j = t + k * 256;
            float ig = sigmoidf_(gates2[j]);
            float fg = sigmoidf_(gates2[H + j]);
            float gg = tanhf(gates2[2*H + j]);
            float og = sigmoidf_(gates2[3*H + j]);
            float c  = fg * cell[H + j] + ig * gg;  // cell[1]
            float h  = og * tanhf(c);
            hs[j] = h;
            if (blockIdx.x == 0) {
                out[OFF_H1 + j] = h;
                out[OFF_C1 + j] = c;
            }
        }
        __syncthreads();
        const float4* h4 = (const float4*)hs;
        // 32 rows per block, 8 per wave
        #pragma unroll 2
        for (int k = 0; k < 8; ++k) {
            const int row = blockIdx.x * 32 + wv * 8 + k;
            const float4* __restrict__ Wr = (const float4*)(W1 + (size_t)row * H);
            float acc = dot4(ntload4(&Wr[lane]),      h4[lane])
                      + dot4(ntload4(&Wr[lane + 64]), h4[lane + 64]);
            #pragma unroll
            for (int off = 32; off > 0; off >>= 1) acc += __shfl_down(acc, off);
            if (lane == 0) out[row] = acc + b1[row];
        }
        if (blockIdx.x == 0) {
            float p = hs[t] * W2[t] + hs[t + 256] * W2[t + 256];
            #pragma unroll
            for (int off = 32; off > 0; off >>= 1) p += __shfl_down(p, off);
            __syncthreads();
            if (lane == 0) red[wv] = p;
            __syncthreads();
            if (t == 0) {
                float v = red[0] + red[1] + red[2] + red[3] + b2[0];
                out[OFF_STEP] = fminf(fmaxf(v, 1e-7f), 0.005f);
            }
        }
    }
}

extern "C" void kernel_launch(void* const* d_in, const int* in_sizes, int n_in,
                              void* d_out, int out_size, void* d_ws, size_t ws_size,
                              hipStream_t stream) {
    const float* dL_dU  = (const float*)d_in[0];
    const float* dL_dV  = (const float*)d_in[1];
    const float* hidden = (const float*)d_in[2];
    const float* cell   = (const float*)d_in[3];
    const float* W_ih1  = (const float*)d_in[4];
    const float* W_hh1  = (const float*)d_in[5];
    const float* b_ih1  = (const float*)d_in[6];
    const float* b_hh1  = (const float*)d_in[7];
    const float* W_ih2  = (const float*)d_in[8];
    const float* W_hh2  = (const float*)d_in[9];
    const float* b_ih2  = (const float*)d_in[10];
    const float* b_hh2  = (const float*)d_in[11];
    const float* W1     = (const float*)d_in[12];
    const float* b1     = (const float*)d_in[13];
    const float* W2     = (const float*)d_in[14];
    const float* b2     = (const float*)d_in[15];
    const float* W3     = (const float*)d_in[16];
    const float* b3     = (const float*)d_in[17];

    float* out = (float*)d_out;
    float* ws  = (float*)d_ws;
    float* gates1 = ws;             // 2048
    float* gates2 = ws + 2048;      // 2048

    void* args[] = {
        (void*)&dL_dU, (void*)&dL_dV, (void*)&hidden, (void*)&cell,
        (void*)&W_ih1, (void*)&W_hh1, (void*)&b_ih1, (void*)&b_hh1,
        (void*)&W_ih2, (void*)&W_hh2, (void*)&b_ih2, (void*)&b_hh2,
        (void*)&W1, (void*)&b1, (void*)&W2, (void*)&b2,
        (void*)&W3, (void*)&b3,
        (void*)&gates1, (void*)&gates2, (void*)&out
    };
    hipLaunchCooperativeKernel((const void*)k_fused, dim3(512), dim3(256),
                               args, 0, stream);
    (void)in_sizes; (void)n_in; (void)out_size; (void)ws_size;
}

// Round 8
// 189.233 us; speedup vs baseline: 1.6551x; 1.6551x over previous
//
#include <hip/hip_runtime.h>
#include <math.h>

#define D_IN 131072
#define H 512
#define G4 2048      // 4*H
#define OUTN 16384   // 128*128

// ---- output flat offsets ----
// g: [0,16384)  step:16384  m_c:16385  h0:@16386  h1:@16898  c0:@17410  c1:@17922
#define OFF_STEP 16384
#define OFF_MC   16385
#define OFF_H0   16386
#define OFF_H1   16898
#define OFF_C0   17410
#define OFF_C1   17922

__device__ __forceinline__ float sigmoidf_(float x) {
    return 1.0f / (1.0f + __expf(-x));
}

__device__ __forceinline__ float dot4(float4 a, float4 b) {
    return a.x*b.x + a.y*b.y + a.z*b.z + a.w*b.w;
}

// non-temporal float4 load (single-use weight streams: don't pollute L2)
typedef float f4v __attribute__((ext_vector_type(4)));
__device__ __forceinline__ float4 ntload4(const float4* p) {
    f4v v = __builtin_nontemporal_load((const f4v*)p);
    float4 r; r.x = v.x; r.y = v.y; r.z = v.z; r.w = v.w;
    return r;
}

// ---------------------------------------------------------------------------
// K1: gates1[r] = W_ih1[r,:].grad + W_hh1[r,:].hidden0 + b_ih1[r] + b_hh1[r]
// 512 blocks x 256 threads; each block does 4 CONTIGUOUS rows sequentially
// (512 concurrent 2 MB HBM streams). W loads NT (L2-bypass: keeps x resident).
// Barrier-free row loop: each (row, wave) writes a distinct red[] slot; one
// __syncthreads at the end -> the vmem stream never drains mid-block.
// ---------------------------------------------------------------------------
__global__ __launch_bounds__(256) void k_gemv1p(
    const float* __restrict__ U, const float* __restrict__ V,
    const float* __restrict__ Wih, const float* __restrict__ Whh,
    const float* __restrict__ bih, const float* __restrict__ bhh,
    const float* __restrict__ hidden, float* __restrict__ gates)
{
    __shared__ float red[16];
    const int t = threadIdx.x;
    const int wv = t >> 6, lane = t & 63;
    const float4* __restrict__ U4 = (const float4*)U;
    const float4* __restrict__ V4 = (const float4*)V;
    const float4* __restrict__ h4 = (const float4*)hidden;  // hidden[0]
    #pragma unroll 1
    for (int i = 0; i < 4; ++i) {
        const int r = blockIdx.x * 4 + i;
        const float4* __restrict__ Wrow = (const float4*)(Wih + (size_t)r * D_IN);
        float acc = 0.0f;
        #pragma unroll 4
        for (int idx = t; idx < 16384; idx += 256) {
            acc += dot4(ntload4(&Wrow[idx]), U4[idx]);
        }
        #pragma unroll 4
        for (int idx = t; idx < 16384; idx += 256) {
            acc += dot4(ntload4(&Wrow[idx + 16384]), V4[idx]);
        }
        if (t < 128) {
            const float4* __restrict__ Wh4 = (const float4*)(Whh + (size_t)r * H);
            acc += dot4(ntload4(&Wh4[t]), h4[t]);
        }
        #pragma unroll
        for (int off = 32; off > 0; off >>= 1) acc += __shfl_down(acc, off);
        if (lane == 0) red[i * 4 + wv] = acc;   // distinct slot: no barrier
    }
    __syncthreads();
    if (t < 4) {
        const int r = blockIdx.x * 4 + t;
        gates[r] = red[t*4] + red[t*4+1] + red[t*4+2] + red[t*4+3]
                 + bih[r] + bhh[r];
    }
}

// ---------------------------------------------------------------------------
// K2: fused cell1 + gemv2. 128 blocks x 1024 threads (16 waves = 16 rows).
// ---------------------------------------------------------------------------
__global__ __launch_bounds__(1024) void k_l2fused(
    const float* __restrict__ gates1, const float* __restrict__ cell_in,
    const float* __restrict__ hidden,
    const float* __restrict__ Wih2, const float* __restrict__ Whh2,
    const float* __restrict__ bih2, const float* __restrict__ bhh2,
    const float* __restrict__ W3, const float* __restrict__ b3,
    float* __restrict__ gates2, float* __restrict__ out)
{
    __shared__ float h0s[H];
    __shared__ float red[16];
    const int tid = threadIdx.x;
    if (tid < H) {
        float ig = sigmoidf_(gates1[tid]);
        float fg = sigmoidf_(gates1[H + tid]);
        float gg = tanhf(gates1[2*H + tid]);
        float og = sigmoidf_(gates1[3*H + tid]);
        float c  = fg * cell_in[tid] + ig * gg;   // cell[0]
        float h  = og * tanhf(c);
        h0s[tid] = h;
        if (blockIdx.x == 0) {
            out[OFF_H0 + tid] = h;
            out[OFF_C0 + tid] = c;
        }
    }
    __syncthreads();
    const int wv = tid >> 6, lane = tid & 63;
    const int row = blockIdx.x * 16 + wv;
    const float4* __restrict__ Wr = (const float4*)(Wih2 + (size_t)row * H);
    const float4* __restrict__ Hr = (const float4*)(Whh2 + (size_t)row * H);
    const float4* h4 = (const float4*)h0s;
    const float4* __restrict__ y4 = (const float4*)(hidden + H);  // hidden[1]
    float acc = dot4(ntload4(&Wr[lane]),      h4[lane])
              + dot4(ntload4(&Hr[lane]),      y4[lane])
              + dot4(ntload4(&Wr[lane + 64]), h4[lane + 64])
              + dot4(ntload4(&Hr[lane + 64]), y4[lane + 64]);
    #pragma unroll
    for (int off = 32; off > 0; off >>= 1) acc += __shfl_down(acc, off);
    if (lane == 0) gates2[row] = acc + bih2[row] + bhh2[row];

    if (blockIdx.x == 0) {
        float p = (tid < H) ? h0s[tid] * W3[tid] : 0.0f;
        #pragma unroll
        for (int off = 32; off > 0; off >>= 1) p += __shfl_down(p, off);
        if (lane == 0) red[wv] = p;
        __syncthreads();
        if (tid == 0) {
            float v = b3[0];
            #pragma unroll
            for (int i = 0; i < 16; ++i) v += red[i];
            v = fminf(fmaxf(v, 0.0f), 1.0f);
            out[OFF_MC] = fminf(2.0f * v, 1.0f);
        }
    }
}

// ---------------------------------------------------------------------------
// K3: fused cell2 + out_g. 1024 blocks x 1024 threads (16 waves = 16 rows).
// Every block recomputes h1 from gates2 into LDS; block 0 writes h1/c1 and
// step_size.
// ---------------------------------------------------------------------------
__global__ __launch_bounds__(1024) void k_l3fused(
    const float* __restrict__ gates2, const float* __restrict__ cell_in,
    const float* __restrict__ W1, const float* __restrict__ b1,
    const float* __restrict__ W2, const float* __restrict__ b2,
    float* __restrict__ out)
{
    __shared__ float h1s[H];
    __shared__ float red[16];
    const int tid = threadIdx.x;
    if (tid < H) {
        float ig = sigmoidf_(gates2[tid]);
        float fg = sigmoidf_(gates2[H + tid]);
        float gg = tanhf(gates2[2*H + tid]);
        float og = sigmoidf_(gates2[3*H + tid]);
        float c  = fg * cell_in[H + tid] + ig * gg;  // cell[1]
        float h  = og * tanhf(c);
        h1s[tid] = h;
        if (blockIdx.x == 0) {
            out[OFF_H1 + tid] = h;
            out[OFF_C1 + tid] = c;
        }
    }
    __syncthreads();
    const int wv = tid >> 6, lane = tid & 63;
    const int row = blockIdx.x * 16 + wv;
    const float4* __restrict__ Wr = (const float4*)(W1 + (size_t)row * H);
    const float4* h4 = (const float4*)h1s;
    float acc = dot4(ntload4(&Wr[lane]),      h4[lane])
              + dot4(ntload4(&Wr[lane + 64]), h4[lane + 64]);
    #pragma unroll
    for (int off = 32; off > 0; off >>= 1) acc += __shfl_down(acc, off);
    if (lane == 0) out[row] = acc + b1[row];

    if (blockIdx.x == 0) {
        float p = (tid < H) ? h1s[tid] * W2[tid] : 0.0f;
        #pragma unroll
        for (int off = 32; off > 0; off >>= 1) p += __shfl_down(p, off);
        if (lane == 0) red[wv] = p;
        __syncthreads();
        if (tid == 0) {
            float v = b2[0];
            #pragma unroll
            for (int i = 0; i < 16; ++i) v += red[i];
            out[OFF_STEP] = fminf(fmaxf(v, 1e-7f), 0.005f);
        }
    }
}

extern "C" void kernel_launch(void* const* d_in, const int* in_sizes, int n_in,
                              void* d_out, int out_size, void* d_ws, size_t ws_size,
                              hipStream_t stream) {
    const float* dL_dU  = (const float*)d_in[0];
    const float* dL_dV  = (const float*)d_in[1];
    const float* hidden = (const float*)d_in[2];
    const float* cell   = (const float*)d_in[3];
    const float* W_ih1  = (const float*)d_in[4];
    const float* W_hh1  = (const float*)d_in[5];
    const float* b_ih1  = (const float*)d_in[6];
    const float* b_hh1  = (const float*)d_in[7];
    const float* W_ih2  = (const float*)d_in[8];
    const float* W_hh2  = (const float*)d_in[9];
    const float* b_ih2  = (const float*)d_in[10];
    const float* b_hh2  = (const float*)d_in[11];
    const float* W1     = (const float*)d_in[12];
    const float* b1     = (const float*)d_in[13];
    const float* W2     = (const float*)d_in[14];
    const float* b2     = (const float*)d_in[15];
    const float* W3     = (const float*)d_in[16];
    const float* b3     = (const float*)d_in[17];

    float* out = (float*)d_out;
    float* ws  = (float*)d_ws;
    float* gates1 = ws;             // 2048
    float* gates2 = ws + 2048;      // 2048

    k_gemv1p<<<512, 256, 0, stream>>>(dL_dU, dL_dV, W_ih1, W_hh1,
                                      b_ih1, b_hh1, hidden, gates1);
    k_l2fused<<<G4 / 16, 1024, 0, stream>>>(gates1, cell, hidden,
                                            W_ih2, W_hh2, b_ih2, b_hh2,
                                            W3, b3, gates2, out);
    k_l3fused<<<OUTN / 16, 1024, 0, stream>>>(gates2, cell, W1, b1, W2, b2, out);
    (void)in_sizes; (void)n_in; (void)out_size; (void)ws_size;
}